// Round 1
// baseline (3476.194 us; speedup 1.0000x reference)
//
#include <hip/hip_runtime.h>

#define BB 8
#define NN 8192
#define NPOINT 2048
#define NSAMPLE 32
#define CC 64

// ---------------- kernel 0a: transpose features (B,C,N) -> (B,N,C) ----------
__global__ __launch_bounds__(256) void k_transpose(const float* __restrict__ f,
                                                   float* __restrict__ ft) {
  __shared__ float tile[64][65];
  int b = blockIdx.y;
  int p0 = blockIdx.x * 64;
  int tx = threadIdx.x, ty = threadIdx.y;
  const float* fb = f + (size_t)b * CC * NN;
#pragma unroll
  for (int i = 0; i < 16; ++i) {
    int c = i * 4 + ty;
    tile[c][tx] = fb[(size_t)c * NN + p0 + tx];
  }
  __syncthreads();
  float* fo = ft + ((size_t)b * NN + p0) * CC;
#pragma unroll
  for (int i = 0; i < 16; ++i) {
    int pl = i * 4 + ty;
    fo[(size_t)pl * CC + tx] = tile[tx][pl];
  }
}

// ---------------- kernel 0b: permute/pad W1 (64,67) -> (64,68) --------------
// new x layout: [f0..f63, dx, dy, dz, 0]; orig x = [dx,dy,dz,f0..f63]
__global__ void k_permW1(const float* __restrict__ W1, float* __restrict__ W1p) {
  int i = blockIdx.x * 256 + threadIdx.x;
  if (i < 64 * 68) {
    int o = i / 68, k = i % 68;
    float v;
    if (k < 64) v = W1[o * 67 + 3 + k];
    else if (k < 67) v = W1[o * 67 + (k - 64)];
    else v = 0.0f;
    W1p[i] = v;
  }
}

// ---------------- kernel 1: furthest point sampling (exact) -----------------
__global__ __launch_bounds__(512) void k_fps(const float* __restrict__ xyz,
                                             float* __restrict__ newxyz) {
  __shared__ float sx[NN], sy[NN], sz[NN];  // 96 KB
  __shared__ float swd[2][8];
  __shared__ int swi[2][8];
  int b = blockIdx.x;
  const float* X = xyz + (size_t)b * NN * 3;
  int t = threadIdx.x;
  float px[16], py[16], pz[16], dist[16];
#pragma unroll
  for (int j = 0; j < 16; ++j) {
    int p = t + j * 512;
    float x = X[p * 3 + 0], y = X[p * 3 + 1], z = X[p * 3 + 2];
    px[j] = x; py[j] = y; pz[j] = z;
    sx[p] = x; sy[p] = y; sz[p] = z;
    dist[j] = __builtin_inff();
  }
  __syncthreads();
  int lane = t & 63, w = t >> 6;
  if (t == 0) {
    newxyz[(size_t)b * NPOINT * 3 + 0] = sx[0];
    newxyz[(size_t)b * NPOINT * 3 + 1] = sy[0];
    newxyz[(size_t)b * NPOINT * 3 + 2] = sz[0];
  }
  int cur = 0;
  for (int it = 1; it < NPOINT; ++it) {
    float cx = sx[cur], cy = sy[cur], cz = sz[cur];
    float bd = -1.0f;
    int bi = 0;
#pragma unroll
    for (int j = 0; j < 16; ++j) {
      // exact numpy order: (dx*dx + dy*dy) + dz*dz, no FMA contraction
      float dx = __fsub_rn(px[j], cx);
      float dy = __fsub_rn(py[j], cy);
      float dz = __fsub_rn(pz[j], cz);
      float d = __fadd_rn(__fadd_rn(__fmul_rn(dx, dx), __fmul_rn(dy, dy)),
                          __fmul_rn(dz, dz));
      float dj = fminf(dist[j], d);
      dist[j] = dj;
      if (dj > bd) { bd = dj; bi = t + (j << 9); }  // strict > => lowest idx wins
    }
#pragma unroll
    for (int off = 1; off < 64; off <<= 1) {
      float od = __shfl_xor(bd, off);
      int oi2 = __shfl_xor(bi, off);
      if (od > bd || (od == bd && oi2 < bi)) { bd = od; bi = oi2; }
    }
    int sel = it & 1;
    if (lane == 0) { swd[sel][w] = bd; swi[sel][w] = bi; }
    __syncthreads();
    // every wave redundantly reduces the 8 per-wave winners (saves a barrier)
    float d8 = (lane < 8) ? swd[sel][lane] : -1.0f;
    int i8 = (lane < 8) ? swi[sel][lane] : 0x7fffffff;
#pragma unroll
    for (int off = 1; off < 8; off <<= 1) {
      float od = __shfl_xor(d8, off);
      int oi2 = __shfl_xor(i8, off);
      if (od > d8 || (od == d8 && oi2 < i8)) { d8 = od; i8 = oi2; }
    }
    int win = __shfl(i8, 0);
    if (t == 0) {
      float* o = newxyz + ((size_t)b * NPOINT + it) * 3;
      o[0] = sx[win]; o[1] = sy[win]; o[2] = sz[win];
    }
    cur = win;
  }
}

// ---------------- kernel 2: ball query (exact, first-32 ascending) ----------
__global__ __launch_bounds__(256) void k_ballq(const float* __restrict__ xyz,
                                               const float* __restrict__ newxyz,
                                               int* __restrict__ idxout) {
  __shared__ int lidx[4][32];
  int w = threadIdx.x >> 6, lane = threadIdx.x & 63;
  int g = blockIdx.x * 4 + w;
  int b = g >> 11, s = g & 2047;
  const float* X = xyz + (size_t)b * NN * 3;
  const float* c = newxyz + ((size_t)b * NPOINT + s) * 3;
  float cx = c[0], cy = c[1], cz = c[2];
  const float r2 = 0.2f * 0.2f;
  int found = 0;
  for (int ch = 0; ch < NN / 64; ++ch) {
    int p = ch * 64 + lane;
    float x = X[p * 3 + 0], y = X[p * 3 + 1], z = X[p * 3 + 2];
    float dx = __fsub_rn(cx, x);
    float dy = __fsub_rn(cy, y);
    float dz = __fsub_rn(cz, z);
    float d2 = __fadd_rn(__fadd_rn(__fmul_rn(dx, dx), __fmul_rn(dy, dy)),
                         __fmul_rn(dz, dz));
    bool in = d2 < r2;
    unsigned long long m = __ballot(in);
    int rank = __popcll(m & ((1ull << lane) - 1ull));
    int slot = found + rank;
    if (in && slot < NSAMPLE) lidx[w][slot] = p;
    found += __popcll(m);
    if (found >= NSAMPLE) break;
  }
  int nf = found < NSAMPLE ? found : NSAMPLE;
  if (lane < NSAMPLE) {
    int v = (nf == 0) ? 0 : lidx[w][lane < nf ? lane : 0];
    idxout[(size_t)g * NSAMPLE + lane] = v;
  }
}

// ---------------- kernel 3: fused gather + 3-layer MLP + maxpool ------------
// wave = one group (64 lanes = 16 o-blocks x 4 s-interleaves)
__global__ __launch_bounds__(256) void k_mlp(
    const float* __restrict__ featsT, const float* __restrict__ xyz,
    const float* __restrict__ newxyz, const int* __restrict__ idx,
    const float* __restrict__ W1p, const float* __restrict__ b1,
    const float* __restrict__ W2, const float* __restrict__ b2,
    const float* __restrict__ W3, const float* __restrict__ b3,
    float* __restrict__ outf) {
  __shared__ __align__(16) float xb[4][32][68];  // 34.8 KB
  int w = threadIdx.x >> 6, lane = threadIdx.x & 63;
  int g = blockIdx.x * 4 + w;
  int b = g >> 11, s2 = g & 2047;

  // stage x = [feats(64) | dxyz(3) | 0] (wave-local, no barrier needed)
  {
    int sl = lane & 31, half = lane >> 5;
    int p = idx[(size_t)g * NSAMPLE + sl];
    const float4* src = (const float4*)(featsT + (((size_t)b << 13) + p) * 64);
    float4* dst = (float4*)&xb[w][sl][0];
    if (half == 0) {
#pragma unroll
      for (int kt = 0; kt < 8; ++kt) dst[kt] = src[kt];
    } else {
#pragma unroll
      for (int kt = 8; kt < 16; ++kt) dst[kt] = src[kt];
      const float* cp = newxyz + (((size_t)b << 11) + s2) * 3;
      const float* pp = xyz + (((size_t)b << 13) + p) * 3;
      float dx = __fsub_rn(pp[0], cp[0]);
      float dy = __fsub_rn(pp[1], cp[1]);
      float dz = __fsub_rn(pp[2], cp[2]);
      dst[16] = make_float4(dx, dy, dz, 0.0f);
    }
  }
  int si = lane & 3, oi = lane >> 2;
  float* xrow0 = &xb[w][0][0];
  float acc[4][8];

  // ---- layer 1: K=68 ----
#pragma unroll
  for (int r = 0; r < 4; ++r) {
    float bv = b1[oi * 4 + r];
#pragma unroll
    for (int q = 0; q < 8; ++q) acc[r][q] = bv;
  }
  for (int kt = 0; kt < 17; ++kt) {
    float4 wv[4];
#pragma unroll
    for (int r = 0; r < 4; ++r)
      wv[r] = *(const float4*)(W1p + (oi * 4 + r) * 68 + kt * 4);
#pragma unroll
    for (int q = 0; q < 8; ++q) {
      float4 xv = *(const float4*)(xrow0 + (si + 4 * q) * 68 + kt * 4);
#pragma unroll
      for (int r = 0; r < 4; ++r) {
        acc[r][q] = fmaf(wv[r].x, xv.x, acc[r][q]);
        acc[r][q] = fmaf(wv[r].y, xv.y, acc[r][q]);
        acc[r][q] = fmaf(wv[r].z, xv.z, acc[r][q]);
        acc[r][q] = fmaf(wv[r].w, xv.w, acc[r][q]);
      }
    }
  }
#pragma unroll
  for (int q = 0; q < 8; ++q) {
    int s = si + 4 * q;
    float4 v = make_float4(fmaxf(acc[0][q], 0.f), fmaxf(acc[1][q], 0.f),
                           fmaxf(acc[2][q], 0.f), fmaxf(acc[3][q], 0.f));
    *(float4*)(xrow0 + s * 68 + oi * 4) = v;  // a[s][o], cols 0..63
  }

  // ---- layer 2: K=64 ----
#pragma unroll
  for (int r = 0; r < 4; ++r) {
    float bv = b2[oi * 4 + r];
#pragma unroll
    for (int q = 0; q < 8; ++q) acc[r][q] = bv;
  }
  for (int kt = 0; kt < 16; ++kt) {
    float4 wv[4];
#pragma unroll
    for (int r = 0; r < 4; ++r)
      wv[r] = *(const float4*)(W2 + (oi * 4 + r) * 64 + kt * 4);
#pragma unroll
    for (int q = 0; q < 8; ++q) {
      float4 xv = *(const float4*)(xrow0 + (si + 4 * q) * 68 + kt * 4);
#pragma unroll
      for (int r = 0; r < 4; ++r) {
        acc[r][q] = fmaf(wv[r].x, xv.x, acc[r][q]);
        acc[r][q] = fmaf(wv[r].y, xv.y, acc[r][q]);
        acc[r][q] = fmaf(wv[r].z, xv.z, acc[r][q]);
        acc[r][q] = fmaf(wv[r].w, xv.w, acc[r][q]);
      }
    }
  }
#pragma unroll
  for (int q = 0; q < 8; ++q) {
    int s = si + 4 * q;
    float4 v = make_float4(fmaxf(acc[0][q], 0.f), fmaxf(acc[1][q], 0.f),
                           fmaxf(acc[2][q], 0.f), fmaxf(acc[3][q], 0.f));
    *(float4*)(xrow0 + s * 68 + oi * 4) = v;
  }

  // ---- layer 3: K=64, 128 outputs (two passes) + maxpool ----
  float accB[4][8];
#pragma unroll
  for (int r = 0; r < 4; ++r) {
    float bvA = b3[oi * 4 + r];
    float bvB = b3[64 + oi * 4 + r];
#pragma unroll
    for (int q = 0; q < 8; ++q) { acc[r][q] = bvA; accB[r][q] = bvB; }
  }
  for (int kt = 0; kt < 16; ++kt) {
    float4 wa[4], wb[4];
#pragma unroll
    for (int r = 0; r < 4; ++r) {
      wa[r] = *(const float4*)(W3 + (oi * 4 + r) * 64 + kt * 4);
      wb[r] = *(const float4*)(W3 + (64 + oi * 4 + r) * 64 + kt * 4);
    }
#pragma unroll
    for (int q = 0; q < 8; ++q) {
      float4 xv = *(const float4*)(xrow0 + (si + 4 * q) * 68 + kt * 4);
#pragma unroll
      for (int r = 0; r < 4; ++r) {
        acc[r][q] = fmaf(wa[r].x, xv.x, acc[r][q]);
        acc[r][q] = fmaf(wa[r].y, xv.y, acc[r][q]);
        acc[r][q] = fmaf(wa[r].z, xv.z, acc[r][q]);
        acc[r][q] = fmaf(wa[r].w, xv.w, acc[r][q]);
        accB[r][q] = fmaf(wb[r].x, xv.x, accB[r][q]);
        accB[r][q] = fmaf(wb[r].y, xv.y, accB[r][q]);
        accB[r][q] = fmaf(wb[r].z, xv.z, accB[r][q]);
        accB[r][q] = fmaf(wb[r].w, xv.w, accB[r][q]);
      }
    }
  }
#pragma unroll
  for (int r = 0; r < 4; ++r) {
    float mA = acc[r][0], mB = accB[r][0];
#pragma unroll
    for (int q = 1; q < 8; ++q) {
      mA = fmaxf(mA, acc[r][q]);
      mB = fmaxf(mB, accB[r][q]);
    }
    mA = fmaxf(mA, __shfl_xor(mA, 1));
    mA = fmaxf(mA, __shfl_xor(mA, 2));
    mB = fmaxf(mB, __shfl_xor(mB, 1));
    mB = fmaxf(mB, __shfl_xor(mB, 2));
    mA = fmaxf(mA, 0.0f);
    mB = fmaxf(mB, 0.0f);
    if (si == 0) {
      int o = oi * 4 + r;
      outf[(((size_t)b * 128 + o) << 11) + s2] = mA;
      outf[(((size_t)b * 128 + o + 64) << 11) + s2] = mB;
    }
  }
}

extern "C" void kernel_launch(void* const* d_in, const int* in_sizes, int n_in,
                              void* d_out, int out_size, void* d_ws, size_t ws_size,
                              hipStream_t stream) {
  const float* xyz = (const float*)d_in[0];
  const float* feats = (const float*)d_in[1];
  const float* W1 = (const float*)d_in[2];
  const float* b1 = (const float*)d_in[3];
  const float* W2 = (const float*)d_in[4];
  const float* b2 = (const float*)d_in[5];
  const float* W3 = (const float*)d_in[6];
  const float* b3 = (const float*)d_in[7];
  float* out_newxyz = (float*)d_out;
  float* out_feats = (float*)d_out + (size_t)BB * NPOINT * 3;

  char* ws = (char*)d_ws;
  float* featsT = (float*)ws;                        // 16 MB
  float* W1p = (float*)(ws + 16777216);              // 17408 B
  int* idx = (int*)(ws + 16777216 + 17408);          // 2 MB

  dim3 tb(64, 4);
  k_transpose<<<dim3(NN / 64, BB), tb, 0, stream>>>(feats, featsT);
  k_permW1<<<17, 256, 0, stream>>>(W1, W1p);
  k_fps<<<BB, 512, 0, stream>>>(xyz, out_newxyz);
  k_ballq<<<(BB * NPOINT) / 4, 256, 0, stream>>>(xyz, out_newxyz, idx);
  k_mlp<<<(BB * NPOINT) / 4, 256, 0, stream>>>(featsT, xyz, out_newxyz, idx,
                                               W1p, b1, W2, b2, W3, b3, out_feats);
}

// Round 2
// 2199.603 us; speedup vs baseline: 1.5804x; 1.5804x over previous
//
#include <hip/hip_runtime.h>

#define BB 8
#define NN 8192
#define NPOINT 2048
#define NSAMPLE 32
#define CC 64

// ---------------- kernel 0a: transpose features (B,C,N) -> (B,N,C) ----------
__global__ __launch_bounds__(256) void k_transpose(const float* __restrict__ f,
                                                   float* __restrict__ ft) {
  __shared__ float tile[64][65];
  int b = blockIdx.y;
  int p0 = blockIdx.x * 64;
  int tx = threadIdx.x, ty = threadIdx.y;
  const float* fb = f + (size_t)b * CC * NN;
#pragma unroll
  for (int i = 0; i < 16; ++i) {
    int c = i * 4 + ty;
    tile[c][tx] = fb[(size_t)c * NN + p0 + tx];
  }
  __syncthreads();
  float* fo = ft + ((size_t)b * NN + p0) * CC;
#pragma unroll
  for (int i = 0; i < 16; ++i) {
    int pl = i * 4 + ty;
    fo[(size_t)pl * CC + tx] = tile[tx][pl];
  }
}

// ---------------- kernel 0b: permute/pad W1 (64,67) -> (64,68) --------------
__global__ void k_permW1(const float* __restrict__ W1, float* __restrict__ W1p) {
  int i = blockIdx.x * 256 + threadIdx.x;
  if (i < 64 * 68) {
    int o = i / 68, k = i % 68;
    float v;
    if (k < 64) v = W1[o * 67 + 3 + k];
    else if (k < 67) v = W1[o * 67 + (k - 64)];
    else v = 0.0f;
    W1p[i] = v;
  }
}

// ---------------- kernel 1: furthest point sampling (exact, DPP argmax) -----
// 256 threads = 4 waves, 32 pts/lane. Packed (dist_bits<<32 | ~idx) u64 argmax:
// intra-wave via DPP (VALU latency, no DS ops), cross-wave via 4 u64 LDS slots
// + ONE barrier. Double-buffered slots -> no resets, no atomics.
#define DPP_STAGE(ctrl)                                                        \
  {                                                                            \
    unsigned _lo = (unsigned)pk, _hi = (unsigned)(pk >> 32);                   \
    unsigned _lo2 =                                                            \
        (unsigned)__builtin_amdgcn_update_dpp(0, (int)_lo, ctrl, 0xf, 0xf, false); \
    unsigned _hi2 =                                                            \
        (unsigned)__builtin_amdgcn_update_dpp(0, (int)_hi, ctrl, 0xf, 0xf, false); \
    unsigned long long _o = ((unsigned long long)_hi2 << 32) | _lo2;           \
    if (_o > pk) pk = _o;                                                      \
  }

__global__ __launch_bounds__(256) void k_fps(const float* __restrict__ xyz,
                                             float* __restrict__ newxyz) {
  __shared__ float sx[NN], sy[NN], sz[NN];  // 96 KB
  __shared__ __align__(16) unsigned long long wres[2][4];
  int b = blockIdx.x;
  const float* X = xyz + (size_t)b * NN * 3;
  int t = threadIdx.x;
  float px[32], py[32], pz[32], dist[32];
#pragma unroll
  for (int j = 0; j < 32; ++j) {
    int p = t + j * 256;
    float x = X[p * 3 + 0], y = X[p * 3 + 1], z = X[p * 3 + 2];
    px[j] = x; py[j] = y; pz[j] = z;
    sx[p] = x; sy[p] = y; sz[p] = z;
    dist[j] = __builtin_inff();
  }
  __syncthreads();
  if (t == 0) {
    newxyz[(size_t)b * NPOINT * 3 + 0] = sx[0];
    newxyz[(size_t)b * NPOINT * 3 + 1] = sy[0];
    newxyz[(size_t)b * NPOINT * 3 + 2] = sz[0];
  }
  float cx = sx[0], cy = sy[0], cz = sz[0];
  for (int it = 1; it < NPOINT; ++it) {
    // --- update dists + per-lane argmax (two independent chains) ---
    float m0 = -1.0f, m1 = -1.0f;
    int i0 = 0, i1 = 0;
#pragma unroll
    for (int j = 0; j < 32; j += 2) {
      {
        float dx = __fsub_rn(px[j], cx);
        float dy = __fsub_rn(py[j], cy);
        float dz = __fsub_rn(pz[j], cz);
        float d = __fadd_rn(__fadd_rn(__fmul_rn(dx, dx), __fmul_rn(dy, dy)),
                            __fmul_rn(dz, dz));
        float dj = fminf(dist[j], d);
        dist[j] = dj;
        if (dj > m0) { m0 = dj; i0 = t + (j << 8); }
      }
      {
        float dx = __fsub_rn(px[j + 1], cx);
        float dy = __fsub_rn(py[j + 1], cy);
        float dz = __fsub_rn(pz[j + 1], cz);
        float d = __fadd_rn(__fadd_rn(__fmul_rn(dx, dx), __fmul_rn(dy, dy)),
                            __fmul_rn(dz, dz));
        float dj = fminf(dist[j + 1], d);
        dist[j + 1] = dj;
        if (dj > m1) { m1 = dj; i1 = t + ((j + 1) << 8); }
      }
    }
    // pack: (dist_bits << 32) | ~idx  -> u64 max == argmax, lowest idx on tie
    unsigned long long pk0 =
        ((unsigned long long)__float_as_uint(m0) << 32) | (unsigned)(~i0);
    unsigned long long pk1 =
        ((unsigned long long)__float_as_uint(m1) << 32) | (unsigned)(~i1);
    unsigned long long pk = pk0 > pk1 ? pk0 : pk1;
    // --- intra-wave 64-lane max via DPP (VALU only), result in lane 63 ---
    DPP_STAGE(0x111)  // row_shr:1
    DPP_STAGE(0x112)  // row_shr:2
    DPP_STAGE(0x114)  // row_shr:4
    DPP_STAGE(0x118)  // row_shr:8
    DPP_STAGE(0x142)  // row_bcast:15
    DPP_STAGE(0x143)  // row_bcast:31
    unsigned glo = (unsigned)__builtin_amdgcn_readlane((int)(unsigned)pk, 63);
    unsigned ghi = (unsigned)__builtin_amdgcn_readlane((int)(pk >> 32), 63);
    int sel = it & 1;
    if ((t & 63) == 0)
      wres[sel][t >> 6] = ((unsigned long long)ghi << 32) | glo;
    __syncthreads();
    // --- cross-wave: every lane reduces the 4 wave winners ---
    ulonglong2 v0 = *(const ulonglong2*)&wres[sel][0];
    ulonglong2 v1 = *(const ulonglong2*)&wres[sel][2];
    unsigned long long g = v0.x;
    if (v0.y > g) g = v0.y;
    if (v1.x > g) g = v1.x;
    if (v1.y > g) g = v1.y;
    unsigned wi = ~(unsigned)g;
    cx = sx[wi]; cy = sy[wi]; cz = sz[wi];
    if (t == 0) {
      float* o = newxyz + ((size_t)b * NPOINT + it) * 3;
      o[0] = cx; o[1] = cy; o[2] = cz;
    }
  }
}

// ---------------- kernel 2: ball query (exact, first-32 ascending) ----------
__global__ __launch_bounds__(256) void k_ballq(const float* __restrict__ xyz,
                                               const float* __restrict__ newxyz,
                                               int* __restrict__ idxout) {
  __shared__ int lidx[4][32];
  int w = threadIdx.x >> 6, lane = threadIdx.x & 63;
  int g = blockIdx.x * 4 + w;
  int b = g >> 11, s = g & 2047;
  const float* X = xyz + (size_t)b * NN * 3;
  const float* c = newxyz + ((size_t)b * NPOINT + s) * 3;
  float cx = c[0], cy = c[1], cz = c[2];
  const float r2 = 0.2f * 0.2f;
  int found = 0;
  for (int ch = 0; ch < NN / 64; ++ch) {
    int p = ch * 64 + lane;
    float x = X[p * 3 + 0], y = X[p * 3 + 1], z = X[p * 3 + 2];
    float dx = __fsub_rn(cx, x);
    float dy = __fsub_rn(cy, y);
    float dz = __fsub_rn(cz, z);
    float d2 = __fadd_rn(__fadd_rn(__fmul_rn(dx, dx), __fmul_rn(dy, dy)),
                         __fmul_rn(dz, dz));
    bool in = d2 < r2;
    unsigned long long m = __ballot(in);
    int rank = __popcll(m & ((1ull << lane) - 1ull));
    int slot = found + rank;
    if (in && slot < NSAMPLE) lidx[w][slot] = p;
    found += __popcll(m);
    if (found >= NSAMPLE) break;
  }
  int nf = found < NSAMPLE ? found : NSAMPLE;
  if (lane < NSAMPLE) {
    int v = (nf == 0) ? 0 : lidx[w][lane < nf ? lane : 0];
    idxout[(size_t)g * NSAMPLE + lane] = v;
  }
}

// ---------------- kernel 3: fused gather + 3-layer MLP + maxpool ------------
__global__ __launch_bounds__(256) void k_mlp(
    const float* __restrict__ featsT, const float* __restrict__ xyz,
    const float* __restrict__ newxyz, const int* __restrict__ idx,
    const float* __restrict__ W1p, const float* __restrict__ b1,
    const float* __restrict__ W2, const float* __restrict__ b2,
    const float* __restrict__ W3, const float* __restrict__ b3,
    float* __restrict__ outf) {
  __shared__ __align__(16) float xb[4][32][68];  // 34.8 KB
  int w = threadIdx.x >> 6, lane = threadIdx.x & 63;
  int g = blockIdx.x * 4 + w;
  int b = g >> 11, s2 = g & 2047;

  {
    int sl = lane & 31, half = lane >> 5;
    int p = idx[(size_t)g * NSAMPLE + sl];
    const float4* src = (const float4*)(featsT + (((size_t)b << 13) + p) * 64);
    float4* dst = (float4*)&xb[w][sl][0];
    if (half == 0) {
#pragma unroll
      for (int kt = 0; kt < 8; ++kt) dst[kt] = src[kt];
    } else {
#pragma unroll
      for (int kt = 8; kt < 16; ++kt) dst[kt] = src[kt];
      const float* cp = newxyz + (((size_t)b << 11) + s2) * 3;
      const float* pp = xyz + (((size_t)b << 13) + p) * 3;
      float dx = __fsub_rn(pp[0], cp[0]);
      float dy = __fsub_rn(pp[1], cp[1]);
      float dz = __fsub_rn(pp[2], cp[2]);
      dst[16] = make_float4(dx, dy, dz, 0.0f);
    }
  }
  int si = lane & 3, oi = lane >> 2;
  float* xrow0 = &xb[w][0][0];
  float acc[4][8];

  // ---- layer 1: K=68 ----
#pragma unroll
  for (int r = 0; r < 4; ++r) {
    float bv = b1[oi * 4 + r];
#pragma unroll
    for (int q = 0; q < 8; ++q) acc[r][q] = bv;
  }
  for (int kt = 0; kt < 17; ++kt) {
    float4 wv[4];
#pragma unroll
    for (int r = 0; r < 4; ++r)
      wv[r] = *(const float4*)(W1p + (oi * 4 + r) * 68 + kt * 4);
#pragma unroll
    for (int q = 0; q < 8; ++q) {
      float4 xv = *(const float4*)(xrow0 + (si + 4 * q) * 68 + kt * 4);
#pragma unroll
      for (int r = 0; r < 4; ++r) {
        acc[r][q] = fmaf(wv[r].x, xv.x, acc[r][q]);
        acc[r][q] = fmaf(wv[r].y, xv.y, acc[r][q]);
        acc[r][q] = fmaf(wv[r].z, xv.z, acc[r][q]);
        acc[r][q] = fmaf(wv[r].w, xv.w, acc[r][q]);
      }
    }
  }
#pragma unroll
  for (int q = 0; q < 8; ++q) {
    int s = si + 4 * q;
    float4 v = make_float4(fmaxf(acc[0][q], 0.f), fmaxf(acc[1][q], 0.f),
                           fmaxf(acc[2][q], 0.f), fmaxf(acc[3][q], 0.f));
    *(float4*)(xrow0 + s * 68 + oi * 4) = v;
  }

  // ---- layer 2: K=64 ----
#pragma unroll
  for (int r = 0; r < 4; ++r) {
    float bv = b2[oi * 4 + r];
#pragma unroll
    for (int q = 0; q < 8; ++q) acc[r][q] = bv;
  }
  for (int kt = 0; kt < 16; ++kt) {
    float4 wv[4];
#pragma unroll
    for (int r = 0; r < 4; ++r)
      wv[r] = *(const float4*)(W2 + (oi * 4 + r) * 64 + kt * 4);
#pragma unroll
    for (int q = 0; q < 8; ++q) {
      float4 xv = *(const float4*)(xrow0 + (si + 4 * q) * 68 + kt * 4);
#pragma unroll
      for (int r = 0; r < 4; ++r) {
        acc[r][q] = fmaf(wv[r].x, xv.x, acc[r][q]);
        acc[r][q] = fmaf(wv[r].y, xv.y, acc[r][q]);
        acc[r][q] = fmaf(wv[r].z, xv.z, acc[r][q]);
        acc[r][q] = fmaf(wv[r].w, xv.w, acc[r][q]);
      }
    }
  }
#pragma unroll
  for (int q = 0; q < 8; ++q) {
    int s = si + 4 * q;
    float4 v = make_float4(fmaxf(acc[0][q], 0.f), fmaxf(acc[1][q], 0.f),
                           fmaxf(acc[2][q], 0.f), fmaxf(acc[3][q], 0.f));
    *(float4*)(xrow0 + s * 68 + oi * 4) = v;
  }

  // ---- layer 3: K=64, 128 outputs (two passes) + maxpool ----
  float accB[4][8];
#pragma unroll
  for (int r = 0; r < 4; ++r) {
    float bvA = b3[oi * 4 + r];
    float bvB = b3[64 + oi * 4 + r];
#pragma unroll
    for (int q = 0; q < 8; ++q) { acc[r][q] = bvA; accB[r][q] = bvB; }
  }
  for (int kt = 0; kt < 16; ++kt) {
    float4 wa[4], wb[4];
#pragma unroll
    for (int r = 0; r < 4; ++r) {
      wa[r] = *(const float4*)(W3 + (oi * 4 + r) * 64 + kt * 4);
      wb[r] = *(const float4*)(W3 + (64 + oi * 4 + r) * 64 + kt * 4);
    }
#pragma unroll
    for (int q = 0; q < 8; ++q) {
      float4 xv = *(const float4*)(xrow0 + (si + 4 * q) * 68 + kt * 4);
#pragma unroll
      for (int r = 0; r < 4; ++r) {
        acc[r][q] = fmaf(wa[r].x, xv.x, acc[r][q]);
        acc[r][q] = fmaf(wa[r].y, xv.y, acc[r][q]);
        acc[r][q] = fmaf(wa[r].z, xv.z, acc[r][q]);
        acc[r][q] = fmaf(wa[r].w, xv.w, acc[r][q]);
        accB[r][q] = fmaf(wb[r].x, xv.x, accB[r][q]);
        accB[r][q] = fmaf(wb[r].y, xv.y, accB[r][q]);
        accB[r][q] = fmaf(wb[r].z, xv.z, accB[r][q]);
        accB[r][q] = fmaf(wb[r].w, xv.w, accB[r][q]);
      }
    }
  }
#pragma unroll
  for (int r = 0; r < 4; ++r) {
    float mA = acc[r][0], mB = accB[r][0];
#pragma unroll
    for (int q = 1; q < 8; ++q) {
      mA = fmaxf(mA, acc[r][q]);
      mB = fmaxf(mB, accB[r][q]);
    }
    mA = fmaxf(mA, __shfl_xor(mA, 1));
    mA = fmaxf(mA, __shfl_xor(mA, 2));
    mB = fmaxf(mB, __shfl_xor(mB, 1));
    mB = fmaxf(mB, __shfl_xor(mB, 2));
    mA = fmaxf(mA, 0.0f);
    mB = fmaxf(mB, 0.0f);
    if (si == 0) {
      int o = oi * 4 + r;
      outf[(((size_t)b * 128 + o) << 11) + s2] = mA;
      outf[(((size_t)b * 128 + o + 64) << 11) + s2] = mB;
    }
  }
}

extern "C" void kernel_launch(void* const* d_in, const int* in_sizes, int n_in,
                              void* d_out, int out_size, void* d_ws, size_t ws_size,
                              hipStream_t stream) {
  const float* xyz = (const float*)d_in[0];
  const float* feats = (const float*)d_in[1];
  const float* W1 = (const float*)d_in[2];
  const float* b1 = (const float*)d_in[3];
  const float* W2 = (const float*)d_in[4];
  const float* b2 = (const float*)d_in[5];
  const float* W3 = (const float*)d_in[6];
  const float* b3 = (const float*)d_in[7];
  float* out_newxyz = (float*)d_out;
  float* out_feats = (float*)d_out + (size_t)BB * NPOINT * 3;

  char* ws = (char*)d_ws;
  float* featsT = (float*)ws;                        // 16 MB
  float* W1p = (float*)(ws + 16777216);              // 17408 B
  int* idx = (int*)(ws + 16777216 + 17408);          // 2 MB

  dim3 tb(64, 4);
  k_transpose<<<dim3(NN / 64, BB), tb, 0, stream>>>(feats, featsT);
  k_permW1<<<17, 256, 0, stream>>>(W1, W1p);
  k_fps<<<BB, 256, 0, stream>>>(xyz, out_newxyz);
  k_ballq<<<(BB * NPOINT) / 4, 256, 0, stream>>>(xyz, out_newxyz, idx);
  k_mlp<<<(BB * NPOINT) / 4, 256, 0, stream>>>(featsT, xyz, out_newxyz, idx,
                                               W1p, b1, W2, b2, W3, b3, out_feats);
}